// Round 1
// baseline (245.163 us; speedup 1.0000x reference)
//
#include <hip/hip_runtime.h>
#include <hip/hip_bf16.h>
#include <math.h>

#define N_TOT 8192
#define HALF_N 4096
#define D_DIM 512
#define BM 128
#define BK 32

typedef short bf16x8_t __attribute__((ext_vector_type(8)));
typedef float f32x4_t __attribute__((ext_vector_type(4)));

typedef __attribute__((address_space(1))) unsigned int g_u32;
typedef __attribute__((address_space(3))) unsigned int l_u32;

__device__ __forceinline__ unsigned short f2bf(float x) {
    union { float f; unsigned int u; } v; v.f = x;
    unsigned int r = v.u + 0x7FFFu + ((v.u >> 16) & 1u);
    return (unsigned short)(r >> 16);
}

// Kernel 1: L2-normalize rows of [p1;p2] -> bf16 Z in workspace; zero rowsum.
__global__ __launch_bounds__(256) void k_normalize(
    const float* __restrict__ p1, const float* __restrict__ p2,
    unsigned short* __restrict__ zbf, float* __restrict__ rowsum)
{
    const int w = threadIdx.x >> 6;
    const int lane = threadIdx.x & 63;
    const int row = blockIdx.x * 4 + w;

    if (threadIdx.x < 4) rowsum[blockIdx.x * 4 + threadIdx.x] = 0.0f;

    const float* src = (row < HALF_N) ? (p1 + (size_t)row * D_DIM)
                                      : (p2 + (size_t)(row - HALF_N) * D_DIM);
    float4 a = *(const float4*)(src + lane * 4);
    float4 b = *(const float4*)(src + 256 + lane * 4);
    float s = a.x*a.x + a.y*a.y + a.z*a.z + a.w*a.w
            + b.x*b.x + b.y*b.y + b.z*b.z + b.w*b.w;
    #pragma unroll
    for (int m = 1; m < 64; m <<= 1) s += __shfl_xor(s, m, 64);
    float inv = 1.0f / fmaxf(sqrtf(s), 1e-8f);

    ushort4 oa, ob;
    oa.x = f2bf(a.x * inv); oa.y = f2bf(a.y * inv);
    oa.z = f2bf(a.z * inv); oa.w = f2bf(a.w * inv);
    ob.x = f2bf(b.x * inv); ob.y = f2bf(b.y * inv);
    ob.z = f2bf(b.z * inv); ob.w = f2bf(b.w * inv);
    unsigned short* dst = zbf + (size_t)row * D_DIM;
    *(ushort4*)(dst + lane * 4) = oa;
    *(ushort4*)(dst + 256 + lane * 4) = ob;
}

// Kernel 2: sim = Z * Z^T tile-by-tile (128x128, bf16 MFMA 16x16x32),
// fused epilogue: exp (diag masked), per-row sum via atomics, pos extraction.
__global__ __launch_bounds__(256) void k_gemm(
    const unsigned short* __restrict__ zbf,
    float* __restrict__ rowsum, float* __restrict__ pos)
{
    __shared__ __align__(16) unsigned short As[BM * BK];
    __shared__ __align__(16) unsigned short Bs[BM * BK];

    const int tid = threadIdx.x;
    const int lane = tid & 63;
    const int w = tid >> 6;
    const int wr = w >> 1, wc = w & 1;
    const int rowBase = blockIdx.y * BM;
    const int colBase = blockIdx.x * BM;
    const int q = lane >> 4, l15 = lane & 15;

    f32x4_t acc[4][4] = {};

    // staging element indices (bf16 elems); two 16B chunks per thread per tile
    const int e0 = tid * 8;
    const int e1 = (256 + tid) * 8;
    const int r0 = e0 >> 5, c0 = e0 & 31;
    const int r1 = e1 >> 5, c1 = e1 & 31;

    for (int kb = 0; kb < D_DIM; kb += BK) {
        const unsigned short* ga0 = zbf + (size_t)(rowBase + r0) * D_DIM + kb + c0;
        const unsigned short* ga1 = zbf + (size_t)(rowBase + r1) * D_DIM + kb + c1;
        const unsigned short* gb0 = zbf + (size_t)(colBase + r0) * D_DIM + kb + c0;
        const unsigned short* gb1 = zbf + (size_t)(colBase + r1) * D_DIM + kb + c1;
        __builtin_amdgcn_global_load_lds((const g_u32*)ga0, (l_u32*)&As[e0], 16, 0, 0);
        __builtin_amdgcn_global_load_lds((const g_u32*)ga1, (l_u32*)&As[e1], 16, 0, 0);
        __builtin_amdgcn_global_load_lds((const g_u32*)gb0, (l_u32*)&Bs[e0], 16, 0, 0);
        __builtin_amdgcn_global_load_lds((const g_u32*)gb1, (l_u32*)&Bs[e1], 16, 0, 0);
        __syncthreads();

        bf16x8_t af[4], bfr[4];
        #pragma unroll
        for (int i = 0; i < 4; i++) {
            af[i]  = *(const bf16x8_t*)&As[(wr * 64 + i * 16 + l15) * BK + q * 8];
            bfr[i] = *(const bf16x8_t*)&Bs[(wc * 64 + i * 16 + l15) * BK + q * 8];
        }
        #pragma unroll
        for (int i = 0; i < 4; i++)
            #pragma unroll
            for (int j = 0; j < 4; j++)
                acc[i][j] = __builtin_amdgcn_mfma_f32_16x16x32_bf16(af[i], bfr[j], acc[i][j], 0, 0, 0);
        __syncthreads();
    }

    // Epilogue: C/D layout (16x16x32): col = lane&15, row = (lane>>4)*4 + reg
    #pragma unroll
    for (int i = 0; i < 4; i++) {
        #pragma unroll
        for (int r = 0; r < 4; r++) {
            const int row = rowBase + wr * 64 + i * 16 + q * 4 + r;
            const int posCol = (row + HALF_N) & (N_TOT - 1);
            float s = 0.0f;
            #pragma unroll
            for (int j = 0; j < 4; j++) {
                const int col = colBase + wc * 64 + j * 16 + l15;
                const float c = acc[i][j][r];
                if (col != row) s += __expf(c);
                if (col == posCol) pos[row] = c;
            }
            s += __shfl_xor(s, 1); s += __shfl_xor(s, 2);
            s += __shfl_xor(s, 4); s += __shfl_xor(s, 8);
            if (l15 == 0) atomicAdd(&rowsum[row], s);
        }
    }
}

// Kernel 3: mean over rows of (log(rowsum) - pos) -> scalar
__global__ __launch_bounds__(256) void k_finalize(
    const float* __restrict__ rowsum, const float* __restrict__ pos,
    float* __restrict__ out)
{
    const int t = threadIdx.x;
    float s = 0.0f;
    for (int i = t; i < N_TOT; i += 256) s += logf(rowsum[i]) - pos[i];
    #pragma unroll
    for (int m = 1; m < 64; m <<= 1) s += __shfl_xor(s, m, 64);
    __shared__ float red[4];
    if ((t & 63) == 0) red[t >> 6] = s;
    __syncthreads();
    if (t == 0) out[0] = (red[0] + red[1] + red[2] + red[3]) * (1.0f / (float)N_TOT);
}

extern "C" void kernel_launch(void* const* d_in, const int* in_sizes, int n_in,
                              void* d_out, int out_size, void* d_ws, size_t ws_size,
                              hipStream_t stream) {
    const float* p1 = (const float*)d_in[0];
    const float* p2 = (const float*)d_in[1];

    unsigned short* zbf = (unsigned short*)d_ws;                       // 8 MB
    float* rowsum = (float*)((char*)d_ws + (size_t)N_TOT * D_DIM * 2); // 32 KB
    float* pos    = rowsum + N_TOT;                                    // 32 KB

    k_normalize<<<N_TOT / 4, 256, 0, stream>>>(p1, p2, zbf, rowsum);
    k_gemm<<<dim3(N_TOT / BM, N_TOT / BM), 256, 0, stream>>>(zbf, rowsum, pos);
    k_finalize<<<1, 256, 0, stream>>>(rowsum, pos, (float*)d_out);
}

// Round 2
// 146.754 us; speedup vs baseline: 1.6706x; 1.6706x over previous
//
#include <hip/hip_runtime.h>
#include <hip/hip_bf16.h>
#include <math.h>

#define N_TOT 8192
#define HALF_N 4096
#define D_DIM 512
#define BM 128
#define BK 32

typedef short bf16x8_t __attribute__((ext_vector_type(8)));
typedef float f32x4_t __attribute__((ext_vector_type(4)));

typedef __attribute__((address_space(1))) unsigned int g_u32;
typedef __attribute__((address_space(3))) unsigned int l_u32;

__device__ __forceinline__ unsigned short f2bf(float x) {
    union { float f; unsigned int u; } v; v.f = x;
    unsigned int r = v.u + 0x7FFFu + ((v.u >> 16) & 1u);
    return (unsigned short)(r >> 16);
}

// Kernel 1: L2-normalize rows of [p1;p2] -> bf16 Z; zero rowsum and out.
__global__ __launch_bounds__(256) void k_normalize(
    const float* __restrict__ p1, const float* __restrict__ p2,
    unsigned short* __restrict__ zbf, float* __restrict__ rowsum,
    float* __restrict__ out)
{
    const int w = threadIdx.x >> 6;
    const int lane = threadIdx.x & 63;
    const int row = blockIdx.x * 4 + w;

    if (threadIdx.x < 4) rowsum[blockIdx.x * 4 + threadIdx.x] = 0.0f;
    if (blockIdx.x == 0 && threadIdx.x == 0) out[0] = 0.0f;

    const float* src = (row < HALF_N) ? (p1 + (size_t)row * D_DIM)
                                      : (p2 + (size_t)(row - HALF_N) * D_DIM);
    float4 a = *(const float4*)(src + lane * 4);
    float4 b = *(const float4*)(src + 256 + lane * 4);
    float s = a.x*a.x + a.y*a.y + a.z*a.z + a.w*a.w
            + b.x*b.x + b.y*b.y + b.z*b.z + b.w*b.w;
    #pragma unroll
    for (int m = 1; m < 64; m <<= 1) s += __shfl_xor(s, m, 64);
    float inv = 1.0f / fmaxf(sqrtf(s), 1e-8f);

    ushort4 oa, ob;
    oa.x = f2bf(a.x * inv); oa.y = f2bf(a.y * inv);
    oa.z = f2bf(a.z * inv); oa.w = f2bf(a.w * inv);
    ob.x = f2bf(b.x * inv); ob.y = f2bf(b.y * inv);
    ob.z = f2bf(b.z * inv); ob.w = f2bf(b.w * inv);
    unsigned short* dst = zbf + (size_t)row * D_DIM;
    *(ushort4*)(dst + lane * 4) = oa;
    *(ushort4*)(dst + 256 + lane * 4) = ob;
}

// Kernel 2: upper-triangle tiles of sim = Z*Z^T (128x128, bf16 MFMA 16x16x32).
// Off-diagonal tile (by,bx): rowsum[row] += row-sums of exp, rowsum[col] +=
// col-sums of exp (transpose tile). Diagonal tile: row-sums only, diag masked.
// LDS staging uses XOR source-swizzle (gc = cc ^ ((row>>1)&3)) so fragment
// ds_read_b128 spreads over all 8 bank groups (2-way = free) while
// global_load_lds dests stay lane-contiguous.
__global__ __launch_bounds__(256) void k_gemm(
    const unsigned short* __restrict__ zbf,
    float* __restrict__ rowsum, float* __restrict__ pos)
{
    __shared__ __align__(16) unsigned short As[BM * BK];
    __shared__ __align__(16) unsigned short Bs[BM * BK];

    // triangular block mapping: t -> (bx >= by)
    const int t = blockIdx.x;
    int bi = (int)((sqrtf(8.0f * (float)t + 1.0f) - 1.0f) * 0.5f);
    while ((bi + 1) * (bi + 2) / 2 <= t) ++bi;
    while (bi * (bi + 1) / 2 > t) --bi;
    const int bx = bi;                       // col tile (larger)
    const int by = t - bi * (bi + 1) / 2;    // row tile
    const bool isDiag = (bx == by);
    const bool hasPos = (bx - by == 32);

    const int tid = threadIdx.x;
    const int lane = tid & 63;
    const int w = tid >> 6;
    const int wr = w >> 1, wc = w & 1;
    const int rowBase = by * BM;
    const int colBase = bx * BM;
    const int q = lane >> 4, l15 = lane & 15;

    f32x4_t acc[4][4] = {};

    // staging: chunk = 8 bf16 = 16B. dest chunk index = tid (and 256+tid).
    const int ci0 = tid;          // row = ci>>2, cc = ci&3
    const int ci1 = 256 + tid;
    const int r0 = ci0 >> 2, cc0 = ci0 & 3;
    const int r1 = ci1 >> 2, cc1 = ci1 & 3;
    const int gc0 = cc0 ^ ((r0 >> 1) & 3);  // XOR source swizzle
    const int gc1 = cc1 ^ ((r1 >> 1) & 3);

    for (int kb = 0; kb < D_DIM; kb += BK) {
        const unsigned short* ga0 = zbf + (size_t)(rowBase + r0) * D_DIM + kb + gc0 * 8;
        const unsigned short* ga1 = zbf + (size_t)(rowBase + r1) * D_DIM + kb + gc1 * 8;
        const unsigned short* gb0 = zbf + (size_t)(colBase + r0) * D_DIM + kb + gc0 * 8;
        const unsigned short* gb1 = zbf + (size_t)(colBase + r1) * D_DIM + kb + gc1 * 8;
        __builtin_amdgcn_global_load_lds((const g_u32*)ga0, (l_u32*)&As[ci0 * 8], 16, 0, 0);
        __builtin_amdgcn_global_load_lds((const g_u32*)ga1, (l_u32*)&As[ci1 * 8], 16, 0, 0);
        __builtin_amdgcn_global_load_lds((const g_u32*)gb0, (l_u32*)&Bs[ci0 * 8], 16, 0, 0);
        __builtin_amdgcn_global_load_lds((const g_u32*)gb1, (l_u32*)&Bs[ci1 * 8], 16, 0, 0);
        __syncthreads();

        bf16x8_t af[4], bfr[4];
        #pragma unroll
        for (int i = 0; i < 4; i++) {
            const int ra = wr * 64 + i * 16 + l15;
            const int rb = wc * 64 + i * 16 + l15;
            af[i]  = *(const bf16x8_t*)&As[ra * BK + (q ^ ((ra >> 1) & 3)) * 8];
            bfr[i] = *(const bf16x8_t*)&Bs[rb * BK + (q ^ ((rb >> 1) & 3)) * 8];
        }
        #pragma unroll
        for (int i = 0; i < 4; i++)
            #pragma unroll
            for (int j = 0; j < 4; j++)
                acc[i][j] = __builtin_amdgcn_mfma_f32_16x16x32_bf16(af[i], bfr[j], acc[i][j], 0, 0, 0);
        __syncthreads();
    }

    // Epilogue. C/D layout (16x16x32): col = lane&15, row = (lane>>4)*4 + reg.
    float colacc[4] = {0.f, 0.f, 0.f, 0.f};
    #pragma unroll
    for (int i = 0; i < 4; i++) {
        #pragma unroll
        for (int r = 0; r < 4; r++) {
            const int row = rowBase + wr * 64 + i * 16 + q * 4 + r;
            float rs = 0.0f;
            #pragma unroll
            for (int j = 0; j < 4; j++) {
                const int col = colBase + wc * 64 + j * 16 + l15;
                const float c = acc[i][j][r];
                float e = __expf(c);
                if (isDiag && col == row) e = 0.0f;
                rs += e;
                colacc[j] += e;
                if (hasPos && col == row + HALF_N) { pos[row] = c; pos[col] = c; }
            }
            rs += __shfl_xor(rs, 1); rs += __shfl_xor(rs, 2);
            rs += __shfl_xor(rs, 4); rs += __shfl_xor(rs, 8);
            if (l15 == 0) atomicAdd(&rowsum[row], rs);
        }
    }
    if (!isDiag) {
        #pragma unroll
        for (int j = 0; j < 4; j++) {
            float cs = colacc[j];
            cs += __shfl_xor(cs, 16);
            cs += __shfl_xor(cs, 32);
            if (q == 0) atomicAdd(&rowsum[colBase + wc * 64 + j * 16 + l15], cs);
        }
    }
}

// Kernel 3: mean over rows of (log(rowsum) - pos) -> scalar (out pre-zeroed).
__global__ __launch_bounds__(256) void k_finalize(
    const float* __restrict__ rowsum, const float* __restrict__ pos,
    float* __restrict__ out)
{
    const int t = threadIdx.x;
    const int i = blockIdx.x * 256 + t;
    float s = logf(rowsum[i]) - pos[i];
    #pragma unroll
    for (int m = 1; m < 64; m <<= 1) s += __shfl_xor(s, m, 64);
    __shared__ float red[4];
    if ((t & 63) == 0) red[t >> 6] = s;
    __syncthreads();
    if (t == 0)
        atomicAdd(out, (red[0] + red[1] + red[2] + red[3]) * (1.0f / (float)N_TOT));
}

extern "C" void kernel_launch(void* const* d_in, const int* in_sizes, int n_in,
                              void* d_out, int out_size, void* d_ws, size_t ws_size,
                              hipStream_t stream) {
    const float* p1 = (const float*)d_in[0];
    const float* p2 = (const float*)d_in[1];

    unsigned short* zbf = (unsigned short*)d_ws;                       // 8 MB
    float* rowsum = (float*)((char*)d_ws + (size_t)N_TOT * D_DIM * 2); // 32 KB
    float* pos    = rowsum + N_TOT;                                    // 32 KB

    const int nTri = (N_TOT / BM) * (N_TOT / BM + 1) / 2;  // 2080

    k_normalize<<<N_TOT / 4, 256, 0, stream>>>(p1, p2, zbf, rowsum, (float*)d_out);
    k_gemm<<<nTri, 256, 0, stream>>>(zbf, rowsum, pos);
    k_finalize<<<N_TOT / 256, 256, 0, stream>>>(rowsum, pos, (float*)d_out);
}